// Round 13
// baseline (195.101 us; speedup 1.0000x reference)
//
#include <hip/hip_runtime.h>
#include <hip/hip_bf16.h>
#include <math.h>

#define NN 50000
#define NE 800000
#define CC 64
#define GG 128
#define BINS ((NN + 255) / 256)    // 196 bins of 256 target nodes
#define CAPB 4608                  // bin capacity (mean 4096, +8 sigma)
#define EPB 2048                   // edges per binning block
#define GA ((NE + EPB - 1) / EPB)  // 391 binning blocks
#define PL (NN * 32)               // elements per channel-plane (bf16)

typedef __hip_bfloat16 bf16;

__device__ inline unsigned short f2b(float f) {
    bf16 h = __float2bfloat16(f);
    return *reinterpret_cast<unsigned short*>(&h);
}
__device__ inline float blo(unsigned u) { return __uint_as_float(u << 16); }
__device__ inline float bhi(unsigned u) { return __uint_as_float(u & 0xffff0000u); }

// zero bin counters + stats (single block)
__global__ void k_prep(int* bin_cnt, float* stats) {
    int t = threadIdx.x;
    if (t < BINS) bin_cnt[t] = 0;
    if (t < 2 * CC) stats[t] = 0.0f;
}

// bin edges by target>>8; single pass over ei (col staged in LDS)
__global__ __launch_bounds__(256) void k_binA(const int* __restrict__ ei,
                                              const float* __restrict__ w,
                                              int* __restrict__ bin_cnt,
                                              int2* __restrict__ binbuf) {
    __shared__ int hist[BINS], base[BINS], rank[BINS];
    __shared__ int cstg[EPB];
    int t = threadIdx.x;
    for (int b = t; b < BINS; b += 256) { hist[b] = 0; rank[b] = 0; }
    __syncthreads();
    int e0 = blockIdx.x * EPB;
    for (int i = t; i < EPB; i += 256) {
        int e = e0 + i;
        if (e < NE) {
            int c = ei[NE + e];
            cstg[i] = c;
            atomicAdd(&hist[c >> 8], 1);
        }
    }
    __syncthreads();
    for (int b = t; b < BINS; b += 256)
        if (hist[b] > 0) base[b] = atomicAdd(&bin_cnt[b], hist[b]);
    __syncthreads();
    for (int i = t; i < EPB; i += 256) {
        int e = e0 + i;
        if (e >= NE) continue;
        int r = ei[e], c = cstg[i], b = c >> 8;
        int pos = base[b] + atomicAdd(&rank[b], 1);
        if (pos < CAPB)
            binbuf[(size_t)b * CAPB + pos] = make_int2(r | ((c & 255) << 16),
                                                       __float_as_int(w[e]));
    }
}

// one block per bin: LDS counting-sort by (target&255) -> per-node CSR (in place),
// fused weighted degree -> dinv. Zero device atomics.
__global__ __launch_bounds__(256) void k_csr(const int* __restrict__ bin_cnt,
                                             int2* __restrict__ binbuf,
                                             float* __restrict__ dinv,
                                             int* __restrict__ rps,
                                             int* __restrict__ rcnt) {
    __shared__ int2 ed[CAPB];
    __shared__ int hist[256], off[256], rank[256];
    __shared__ float degf[256];
    int g = blockIdx.x, t = threadIdx.x;
    int cnt = min(bin_cnt[g], CAPB);
    int2* bp = binbuf + (size_t)g * CAPB;
    hist[t] = 0; rank[t] = 0; degf[t] = 1.0f;   // deg starts at 1 (self-loop)
    __syncthreads();
    for (int e = t; e < cnt; e += 256) {
        int2 r = bp[e];
        ed[e] = r;
        int low = r.x >> 16;
        atomicAdd(&hist[low], 1);
        atomicAdd(&degf[low], __int_as_float(r.y));
    }
    __syncthreads();
    int v = hist[t];
    off[t] = v;
    __syncthreads();
    for (int o = 1; o < 256; o <<= 1) {        // inclusive scan
        int x = (t >= o) ? off[t - o] : 0;
        __syncthreads();
        off[t] += x;
        __syncthreads();
    }
    int node = g * 256 + t;
    if (node < NN) {
        dinv[node] = rsqrtf(degf[t]);
        rps[node] = g * CAPB + (off[t] - v);   // exclusive start
        rcnt[node] = v;
    }
    for (int e = t; e < cnt; e += 256) {
        int2 r = ed[e];
        int low = r.x >> 16;
        int pos = (off[low] - hist[low]) + atomicAdd(&rank[low], 1);
        bp[pos] = make_int2(r.x & 0xffff, r.y);
    }
}

// y = x @ W^T (bf16, plane layout [2][NN][32]) + fold norm records
__global__ __launch_bounds__(256) void k_linfold(const float* __restrict__ x,
                                                 const float* __restrict__ W,
                                                 const float* __restrict__ dinv,
                                                 const int* __restrict__ rps,
                                                 const int* __restrict__ rcnt,
                                                 const int2* __restrict__ binbuf,
                                                 unsigned* __restrict__ csrc,
                                                 bf16* __restrict__ y) {
    __shared__ float Ws[CC * 65];
    __shared__ float hs[4][CC];
    int tid = threadIdx.x, wv = tid >> 6, j = tid & 63;
    for (int t = tid; t < CC * CC; t += 256)
        Ws[(t >> 6) * 65 + (t & 63)] = W[t];
    int node = blockIdx.x * 4 + wv;
    hs[wv][j] = (node < NN) ? x[node * CC + j] : 0.0f;
    __syncthreads();
    if (node >= NN) return;
    float acc = 0.0f;
    const float* hr = hs[wv];
#pragma unroll
    for (int k = 0; k < CC; k++) acc += hr[k] * Ws[j * 65 + k];
    y[(j >> 5) * PL + node * 32 + (j & 31)] = __float2bfloat16(acc);
    // fold: csrc = src | bf16bits(dinv[src]*w*dinv[node])<<16
    float dn = dinv[node];
    int s = rps[node], n = rcnt[node];
    for (int p = j; p < n; p += 64) {
        int2 rec = binbuf[s + p];
        float nw = dinv[rec.x] * __int_as_float(rec.y) * dn;
        csrc[s + p] = (unsigned)rec.x | ((unsigned)f2b(nw) << 16);
    }
}

// wave per node over ONE 32-channel plane: 16 edges/iter (4 lanes x uint4 per edge).
// Gather working set = 3.2 MB -> fits per-XCD L2.
__global__ __launch_bounds__(256) void k_hopc(const bf16* __restrict__ in,
                                              const float* __restrict__ dinv,
                                              const int* __restrict__ rps,
                                              const int* __restrict__ rcnt,
                                              const unsigned* __restrict__ csrc,
                                              bf16* __restrict__ out) {
    int node = blockIdx.x * 4 + (threadIdx.x >> 6);
    if (node >= NN) return;
    int lane = threadIdx.x & 63;
    int grp = lane >> 2;           // 0..15: edge slot
    int lc = lane & 3;             // uint4 slot (channels 8lc..8lc+7 of plane)
    float dn = dinv[node];
    float a0 = 0, a1 = 0, a2 = 0, a3 = 0, a4 = 0, a5 = 0, a6 = 0, a7 = 0;
    if (grp == 0) {                // self-loop on group 0 only
        uint4 v = *reinterpret_cast<const uint4*>(&in[node * 32 + 8 * lc]);
        float d2 = dn * dn;
        a0 = d2 * blo(v.x); a1 = d2 * bhi(v.x);
        a2 = d2 * blo(v.y); a3 = d2 * bhi(v.y);
        a4 = d2 * blo(v.z); a5 = d2 * bhi(v.z);
        a6 = d2 * blo(v.w); a7 = d2 * bhi(v.w);
    }
    int s = rps[node], n = rcnt[node];
    const unsigned* cp = csrc + s;
    int p = 0;
    for (; p + 16 <= n; p += 16) {
        unsigned rec = cp[p + grp];
        float nw = bhi(rec);
        int src = rec & 0xffff;
        uint4 v = *reinterpret_cast<const uint4*>(&in[src * 32 + 8 * lc]);
        a0 = fmaf(nw, blo(v.x), a0); a1 = fmaf(nw, bhi(v.x), a1);
        a2 = fmaf(nw, blo(v.y), a2); a3 = fmaf(nw, bhi(v.y), a3);
        a4 = fmaf(nw, blo(v.z), a4); a5 = fmaf(nw, bhi(v.z), a5);
        a6 = fmaf(nw, blo(v.w), a6); a7 = fmaf(nw, bhi(v.w), a7);
    }
    if (p < n && grp < n - p) {    // tail: 1..15 edges
        unsigned rec = cp[p + grp];
        float nw = bhi(rec);
        int src = rec & 0xffff;
        uint4 v = *reinterpret_cast<const uint4*>(&in[src * 32 + 8 * lc]);
        a0 = fmaf(nw, blo(v.x), a0); a1 = fmaf(nw, bhi(v.x), a1);
        a2 = fmaf(nw, blo(v.y), a2); a3 = fmaf(nw, bhi(v.y), a3);
        a4 = fmaf(nw, blo(v.z), a4); a5 = fmaf(nw, bhi(v.z), a5);
        a6 = fmaf(nw, blo(v.w), a6); a7 = fmaf(nw, bhi(v.w), a7);
    }
    // combine the 16 edge groups: xor 4, 8, 16, 32
#pragma unroll
    for (int d = 4; d < 64; d <<= 1) {
        a0 += __shfl_xor(a0, d, 64); a1 += __shfl_xor(a1, d, 64);
        a2 += __shfl_xor(a2, d, 64); a3 += __shfl_xor(a3, d, 64);
        a4 += __shfl_xor(a4, d, 64); a5 += __shfl_xor(a5, d, 64);
        a6 += __shfl_xor(a6, d, 64); a7 += __shfl_xor(a7, d, 64);
    }
    if (grp == 0) {
        uint4 ov;
        ov.x = (unsigned)f2b(a0) | ((unsigned)f2b(a1) << 16);
        ov.y = (unsigned)f2b(a2) | ((unsigned)f2b(a3) << 16);
        ov.z = (unsigned)f2b(a4) | ((unsigned)f2b(a5) << 16);
        ov.w = (unsigned)f2b(a6) | ((unsigned)f2b(a7) << 16);
        *reinterpret_cast<uint4*>(&out[node * 32 + 8 * lc]) = ov;
    }
}

__device__ inline int lbound(const int* __restrict__ batch, int g) {
    int lo = 0, hi = NN;
    while (lo < hi) {
        int mid = (lo + hi) >> 1;
        if (batch[mid] < g) lo = mid + 1; else hi = mid;
    }
    return lo;
}

// one block per graph: v = PReLU(h2+b); per-graph sum/max/min + global stats.
// h2 is plane layout [2][NN][32].
__global__ __launch_bounds__(256) void k_poolstat(const bf16* __restrict__ h,
                                                  const float* __restrict__ bvec,
                                                  const float* __restrict__ a,
                                                  const int* __restrict__ batch,
                                                  float* __restrict__ stats,
                                                  float* __restrict__ gsum,
                                                  float* __restrict__ gmax,
                                                  float* __restrict__ gmin,
                                                  int* __restrict__ gcnt) {
    __shared__ float r0[4][CC], r1[4][CC], r2[4][CC];
    __shared__ int sse[2];
    int g = blockIdx.x;
    int tid = threadIdx.x, w = tid >> 6, j = tid & 63;
    if (tid == 0) sse[0] = lbound(batch, g);
    if (tid == 1) sse[1] = lbound(batch, g + 1);
    __syncthreads();
    int s = sse[0], e = sse[1];
    const bf16* hp = h + (j >> 5) * PL + (j & 31);
    float bs = bvec[j], as = a[j];
    float sum = 0.0f, sq = 0.0f, mx = -__builtin_inff(), mn = __builtin_inff();
    for (int i = s + w; i < e; i += 4) {
        float v = __bfloat162float(hp[i * 32]) + bs;
        v = v >= 0.0f ? v : as * v;
        sum += v;
        sq += v * v;
        mx = fmaxf(mx, v);
        mn = fminf(mn, v);
    }
    r0[w][j] = sum; r1[w][j] = mx; r2[w][j] = mn;
    __syncthreads();
    if (w == 0) {
        sum = r0[0][j] + r0[1][j] + r0[2][j] + r0[3][j];
        mx = fmaxf(fmaxf(r1[0][j], r1[1][j]), fmaxf(r1[2][j], r1[3][j]));
        mn = fminf(fminf(r2[0][j], r2[1][j]), fminf(r2[2][j], r2[3][j]));
        gsum[g * CC + j] = sum;
        gmax[g * CC + j] = mx;
        gmin[g * CC + j] = mn;
        if (j == 0) gcnt[g] = e - s;
        atomicAdd(&stats[j], sum);
    }
    __syncthreads();
    r0[w][j] = sq;
    __syncthreads();
    if (w == 0) {
        sq = r0[0][j] + r0[1][j] + r0[2][j] + r0[3][j];
        atomicAdd(&stats[CC + j], sq);
    }
}

// BN affine applied to pooled results
__global__ void k_finish(const float* __restrict__ stats,
                         const float* __restrict__ gamma,
                         const float* __restrict__ beta,
                         const int* __restrict__ gcnt,
                         const float* __restrict__ gsum,
                         const float* __restrict__ gmax,
                         const float* __restrict__ gmin,
                         float* __restrict__ out) {
    int t = blockIdx.x * 256 + threadIdx.x;
    if (t >= GG * CC) return;
    int g = t >> 6, j = t & 63;
    float mean = stats[j] * (1.0f / NN);
    float var = stats[CC + j] * (1.0f / NN) - mean * mean;
    float sc = gamma[j] * rsqrtf(var + 1e-5f);
    float sh = beta[j] - mean * sc;
    int n = gcnt[g];
    if (n > 0) {
        out[g * 2 * CC + j] = sc * (gsum[t] / (float)n) + sh;
        out[g * 2 * CC + CC + j] = (sc >= 0.0f) ? sc * gmax[t] + sh
                                                : sc * gmin[t] + sh;
    } else {
        out[g * 2 * CC + j] = 0.0f;
        out[g * 2 * CC + CC + j] = -__builtin_inff();
    }
}

extern "C" void kernel_launch(void* const* d_in, const int* in_sizes, int n_in,
                              void* d_out, int out_size, void* d_ws, size_t ws_size,
                              hipStream_t stream) {
    const float* x = (const float*)d_in[0];
    const int* ei = (const int*)d_in[1];
    const float* ew = (const float*)d_in[2];
    const int* batch = (const int*)d_in[3];
    const float* W = (const float*)d_in[4];
    const float* b = (const float*)d_in[5];
    const float* a = (const float*)d_in[6];
    const float* gamma = (const float*)d_in[7];
    const float* beta = (const float*)d_in[8];
    float* out = (float*)d_out;

    float* ws = (float*)d_ws;
    float* dinv = ws;
    int* rps = (int*)(ws + 50048);
    int* rcnt = (int*)(ws + 2 * 50048);
    int* bin_cnt = (int*)(ws + 3 * 50048);
    float* stats = ws + 3 * 50048 + 256;
    int* gcnt = (int*)(stats + 256);
    float* gsum = (float*)(gcnt + 256);
    float* gmax = gsum + GG * CC;
    float* gmin = gmax + GG * CC;
    int2* binbuf = (int2*)(gmin + GG * CC);
    unsigned* csrc = (unsigned*)(binbuf + (size_t)BINS * CAPB);
    bf16* y = (bf16*)(csrc + (size_t)BINS * CAPB);
    bf16* h1 = y + (size_t)NN * CC;
    bf16* h2 = h1 + (size_t)NN * CC;

    dim3 blk(256);
    int gH = (NN + 3) / 4;

    k_prep<<<1, blk, 0, stream>>>(bin_cnt, stats);
    k_binA<<<GA, blk, 0, stream>>>(ei, ew, bin_cnt, binbuf);
    k_csr<<<BINS, blk, 0, stream>>>(bin_cnt, binbuf, dinv, rps, rcnt);
    k_linfold<<<gH, blk, 0, stream>>>(x, W, dinv, rps, rcnt, binbuf, csrc, y);

    // hop 1 then hop 2, each as two independent 32-channel planes
    k_hopc<<<gH, blk, 0, stream>>>(y,        dinv, rps, rcnt, csrc, h1);
    k_hopc<<<gH, blk, 0, stream>>>(y + PL,   dinv, rps, rcnt, csrc, h1 + PL);
    k_hopc<<<gH, blk, 0, stream>>>(h1,       dinv, rps, rcnt, csrc, h2);
    k_hopc<<<gH, blk, 0, stream>>>(h1 + PL,  dinv, rps, rcnt, csrc, h2 + PL);

    k_poolstat<<<GG, blk, 0, stream>>>(h2, b, a, batch, stats, gsum, gmax, gmin, gcnt);
    k_finish<<<(GG * CC + 255) / 256, blk, 0, stream>>>(stats, gamma, beta, gcnt,
                                                        gsum, gmax, gmin, out);
}

// Round 14
// 131.075 us; speedup vs baseline: 1.4885x; 1.4885x over previous
//
#include <hip/hip_runtime.h>
#include <hip/hip_bf16.h>
#include <math.h>

#define NN 50000
#define NE 800000
#define CC 64
#define GG 128
#define KP 8                       // pooling partials per graph
#define BINS ((NN + 255) / 256)    // 196 bins of 256 target nodes
#define CAPB 4608                  // bin capacity (mean 4096, +8 sigma)
#define EPB 2048                   // edges per binning block
#define GA ((NE + EPB - 1) / EPB)  // 391 binning blocks

typedef __hip_bfloat16 bf16;

__device__ inline unsigned short f2b(float f) {
    bf16 h = __float2bfloat16(f);
    return *reinterpret_cast<unsigned short*>(&h);
}
__device__ inline float blo(unsigned u) { return __uint_as_float(u << 16); }
__device__ inline float bhi(unsigned u) { return __uint_as_float(u & 0xffff0000u); }

// zero bin counters + stats (single block)
__global__ void k_prep(int* bin_cnt, float* stats) {
    int t = threadIdx.x;
    if (t < BINS) bin_cnt[t] = 0;
    if (t < 2 * CC) stats[t] = 0.0f;
}

// bin edges by target>>8; single pass over ei (col staged in LDS)
__global__ __launch_bounds__(256) void k_binA(const int* __restrict__ ei,
                                              const float* __restrict__ w,
                                              int* __restrict__ bin_cnt,
                                              int2* __restrict__ binbuf) {
    __shared__ int hist[BINS], base[BINS], rank[BINS];
    __shared__ int cstg[EPB];
    int t = threadIdx.x;
    for (int b = t; b < BINS; b += 256) { hist[b] = 0; rank[b] = 0; }
    __syncthreads();
    int e0 = blockIdx.x * EPB;
    for (int i = t; i < EPB; i += 256) {
        int e = e0 + i;
        if (e < NE) {
            int c = ei[NE + e];
            cstg[i] = c;
            atomicAdd(&hist[c >> 8], 1);
        }
    }
    __syncthreads();
    for (int b = t; b < BINS; b += 256)
        if (hist[b] > 0) base[b] = atomicAdd(&bin_cnt[b], hist[b]);
    __syncthreads();
    for (int i = t; i < EPB; i += 256) {
        int e = e0 + i;
        if (e >= NE) continue;
        int r = ei[e], c = cstg[i], b = c >> 8;
        int pos = base[b] + atomicAdd(&rank[b], 1);
        if (pos < CAPB)
            binbuf[(size_t)b * CAPB + pos] = make_int2(r | ((c & 255) << 16),
                                                       __float_as_int(w[e]));
    }
}

// one block per bin: LDS counting-sort by (target&255) -> per-node CSR (in place),
// fused weighted degree -> dinv. Zero device atomics.
__global__ __launch_bounds__(256) void k_csr(const int* __restrict__ bin_cnt,
                                             int2* __restrict__ binbuf,
                                             float* __restrict__ dinv,
                                             int* __restrict__ rps,
                                             int* __restrict__ rcnt) {
    __shared__ int2 ed[CAPB];
    __shared__ int hist[256], off[256], rank[256];
    __shared__ float degf[256];
    int g = blockIdx.x, t = threadIdx.x;
    int cnt = min(bin_cnt[g], CAPB);
    int2* bp = binbuf + (size_t)g * CAPB;
    hist[t] = 0; rank[t] = 0; degf[t] = 1.0f;   // deg starts at 1 (self-loop)
    __syncthreads();
    for (int e = t; e < cnt; e += 256) {
        int2 r = bp[e];
        ed[e] = r;
        int low = r.x >> 16;
        atomicAdd(&hist[low], 1);
        atomicAdd(&degf[low], __int_as_float(r.y));
    }
    __syncthreads();
    int v = hist[t];
    off[t] = v;
    __syncthreads();
    for (int o = 1; o < 256; o <<= 1) {        // inclusive scan
        int x = (t >= o) ? off[t - o] : 0;
        __syncthreads();
        off[t] += x;
        __syncthreads();
    }
    int node = g * 256 + t;
    if (node < NN) {
        dinv[node] = rsqrtf(degf[t]);
        rps[node] = g * CAPB + (off[t] - v);   // exclusive start
        rcnt[node] = v;
    }
    for (int e = t; e < cnt; e += 256) {
        int2 r = ed[e];
        int low = r.x >> 16;
        int pos = (off[low] - hist[low]) + atomicAdd(&rank[low], 1);
        bp[pos] = make_int2(r.x & 0xffff, r.y);
    }
}

// y = x @ W^T (bf16, no bias — bias commutes past the hops) + fold norm records
__global__ __launch_bounds__(256) void k_linfold(const float* __restrict__ x,
                                                 const float* __restrict__ W,
                                                 const float* __restrict__ dinv,
                                                 const int* __restrict__ rps,
                                                 const int* __restrict__ rcnt,
                                                 const int2* __restrict__ binbuf,
                                                 unsigned* __restrict__ csrc,
                                                 bf16* __restrict__ y) {
    __shared__ float Ws[CC * 65];
    __shared__ float hs[4][CC];
    int tid = threadIdx.x, wv = tid >> 6, j = tid & 63;
    for (int t = tid; t < CC * CC; t += 256)
        Ws[(t >> 6) * 65 + (t & 63)] = W[t];
    int node = blockIdx.x * 4 + wv;
    hs[wv][j] = (node < NN) ? x[node * CC + j] : 0.0f;
    __syncthreads();
    if (node >= NN) return;
    float acc = 0.0f;
    const float* hr = hs[wv];
#pragma unroll
    for (int k = 0; k < CC; k++) acc += hr[k] * Ws[j * 65 + k];
    y[node * CC + j] = __float2bfloat16(acc);
    // fold: csrc = src | bf16bits(dinv[src]*w*dinv[node])<<16
    float dn = dinv[node];
    int s = rps[node], n = rcnt[node];
    for (int p = j; p < n; p += 64) {
        int2 rec = binbuf[s + p];
        float nw = dinv[rec.x] * __int_as_float(rec.y) * dn;
        csrc[s + p] = (unsigned)rec.x | ((unsigned)f2b(nw) << 16);
    }
}

// wave per node, 8 edges per iteration: octet (8 lanes x uint4=8bf16) per edge.
__global__ __launch_bounds__(256) void k_hop8(const bf16* __restrict__ in,
                                              const float* __restrict__ dinv,
                                              const int* __restrict__ rps,
                                              const int* __restrict__ rcnt,
                                              const unsigned* __restrict__ csrc,
                                              bf16* __restrict__ out) {
    int node = blockIdx.x * 4 + (threadIdx.x >> 6);
    if (node >= NN) return;
    int lane = threadIdx.x & 63;
    int o = lane >> 3;             // 0..7: edge slot within octet group
    int lc = lane & 7;             // channel-oct (channels 8lc..8lc+7)
    float dn = dinv[node];
    float a0 = 0, a1 = 0, a2 = 0, a3 = 0, a4 = 0, a5 = 0, a6 = 0, a7 = 0;
    if (o == 0) {                  // self-loop on octet 0 only
        uint4 v = *reinterpret_cast<const uint4*>(&in[node * CC + 8 * lc]);
        float d2 = dn * dn;
        a0 = d2 * blo(v.x); a1 = d2 * bhi(v.x);
        a2 = d2 * blo(v.y); a3 = d2 * bhi(v.y);
        a4 = d2 * blo(v.z); a5 = d2 * bhi(v.z);
        a6 = d2 * blo(v.w); a7 = d2 * bhi(v.w);
    }
    int s = rps[node], n = rcnt[node];
    const unsigned* cp = csrc + s;
    int p = 0;
#pragma unroll 2
    for (; p + 8 <= n; p += 8) {
        unsigned rec = cp[p + o];
        float nw = bhi(rec);
        int src = rec & 0xffff;
        uint4 v = *reinterpret_cast<const uint4*>(&in[src * CC + 8 * lc]);
        a0 = fmaf(nw, blo(v.x), a0); a1 = fmaf(nw, bhi(v.x), a1);
        a2 = fmaf(nw, blo(v.y), a2); a3 = fmaf(nw, bhi(v.y), a3);
        a4 = fmaf(nw, blo(v.z), a4); a5 = fmaf(nw, bhi(v.z), a5);
        a6 = fmaf(nw, blo(v.w), a6); a7 = fmaf(nw, bhi(v.w), a7);
    }
    if (p < n && o < n - p) {      // tail: 1..7 edges on octets 0..n-p-1
        unsigned rec = cp[p + o];
        float nw = bhi(rec);
        int src = rec & 0xffff;
        uint4 v = *reinterpret_cast<const uint4*>(&in[src * CC + 8 * lc]);
        a0 = fmaf(nw, blo(v.x), a0); a1 = fmaf(nw, bhi(v.x), a1);
        a2 = fmaf(nw, blo(v.y), a2); a3 = fmaf(nw, bhi(v.y), a3);
        a4 = fmaf(nw, blo(v.z), a4); a5 = fmaf(nw, bhi(v.z), a5);
        a6 = fmaf(nw, blo(v.w), a6); a7 = fmaf(nw, bhi(v.w), a7);
    }
    // combine octets: xor 8, 16, 32
#pragma unroll
    for (int d = 8; d < 64; d <<= 1) {
        a0 += __shfl_xor(a0, d, 64); a1 += __shfl_xor(a1, d, 64);
        a2 += __shfl_xor(a2, d, 64); a3 += __shfl_xor(a3, d, 64);
        a4 += __shfl_xor(a4, d, 64); a5 += __shfl_xor(a5, d, 64);
        a6 += __shfl_xor(a6, d, 64); a7 += __shfl_xor(a7, d, 64);
    }
    if (o == 0) {
        uint4 ov;
        ov.x = (unsigned)f2b(a0) | ((unsigned)f2b(a1) << 16);
        ov.y = (unsigned)f2b(a2) | ((unsigned)f2b(a3) << 16);
        ov.z = (unsigned)f2b(a4) | ((unsigned)f2b(a5) << 16);
        ov.w = (unsigned)f2b(a6) | ((unsigned)f2b(a7) << 16);
        *reinterpret_cast<uint4*>(&out[node * CC + 8 * lc]) = ov;
    }
}

__device__ inline int lbound(const int* __restrict__ batch, int g) {
    int lo = 0, hi = NN;
    while (lo < hi) {
        int mid = (lo + hi) >> 1;
        if (batch[mid] < g) lo = mid + 1; else hi = mid;
    }
    return lo;
}

// grid GG*KP: block (g,k) reduces the k-th eighth of graph g's rows.
// v = PReLU(h2+b); partials psum/psq/pmax/pmin[k][g][CC]. No atomics.
__global__ __launch_bounds__(256) void k_poolstat2(const bf16* __restrict__ h,
                                                   const float* __restrict__ bvec,
                                                   const float* __restrict__ a,
                                                   const int* __restrict__ batch,
                                                   float* __restrict__ psum,
                                                   float* __restrict__ psq,
                                                   float* __restrict__ pmax,
                                                   float* __restrict__ pmin,
                                                   int* __restrict__ gcnt) {
    __shared__ float r0[4][CC], r1[4][CC], r2[4][CC], r3[4][CC];
    __shared__ int sse[2];
    int g = blockIdx.x >> 3, k = blockIdx.x & (KP - 1);
    int tid = threadIdx.x, w = tid >> 6, j = tid & 63;
    if (tid == 0) sse[0] = lbound(batch, g);
    if (tid == 1) sse[1] = lbound(batch, g + 1);
    __syncthreads();
    int s = sse[0], e = sse[1], n = e - s;
    if (tid == 0 && k == 0) gcnt[g] = n;
    int c0 = s + ((n * k) >> 3), c1 = s + ((n * (k + 1)) >> 3);
    float bs = bvec[j], as = a[j];
    float sum = 0.0f, sq = 0.0f, mx = -__builtin_inff(), mn = __builtin_inff();
    for (int i = c0 + w; i < c1; i += 4) {
        float v = __bfloat162float(h[i * CC + j]) + bs;
        v = v >= 0.0f ? v : as * v;
        sum += v;
        sq += v * v;
        mx = fmaxf(mx, v);
        mn = fminf(mn, v);
    }
    r0[w][j] = sum; r1[w][j] = sq; r2[w][j] = mx; r3[w][j] = mn;
    __syncthreads();
    if (w == 0) {
        int o = (k * GG + g) * CC + j;
        psum[o] = r0[0][j] + r0[1][j] + r0[2][j] + r0[3][j];
        psq[o]  = r1[0][j] + r1[1][j] + r1[2][j] + r1[3][j];
        pmax[o] = fmaxf(fmaxf(r2[0][j], r2[1][j]), fmaxf(r2[2][j], r2[3][j]));
        pmin[o] = fminf(fminf(r3[0][j], r3[1][j]), fminf(r3[2][j], r3[3][j]));
    }
}

// grid GG/4: reduce KP partials per (g,j) -> per-graph totals; block-reduced
// global stats atomics (1 per channel per block).
__global__ __launch_bounds__(256) void k_red(const float* __restrict__ psum,
                                             const float* __restrict__ psq,
                                             const float* __restrict__ pmax,
                                             const float* __restrict__ pmin,
                                             float* __restrict__ gsum,
                                             float* __restrict__ gmax,
                                             float* __restrict__ gmin,
                                             float* __restrict__ stats) {
    __shared__ float r0[4][CC], r1[4][CC];
    int tid = threadIdx.x, w = tid >> 6, j = tid & 63;
    int g = blockIdx.x * 4 + w;
    float gs = 0.0f, gq = 0.0f, mx = -__builtin_inff(), mn = __builtin_inff();
#pragma unroll
    for (int k = 0; k < KP; k++) {
        int o = (k * GG + g) * CC + j;
        gs += psum[o];
        gq += psq[o];
        mx = fmaxf(mx, pmax[o]);
        mn = fminf(mn, pmin[o]);
    }
    gsum[g * CC + j] = gs;
    gmax[g * CC + j] = mx;
    gmin[g * CC + j] = mn;
    r0[w][j] = gs; r1[w][j] = gq;
    __syncthreads();
    if (w == 0) {
        atomicAdd(&stats[j], r0[0][j] + r0[1][j] + r0[2][j] + r0[3][j]);
        atomicAdd(&stats[CC + j], r1[0][j] + r1[1][j] + r1[2][j] + r1[3][j]);
    }
}

// BN affine applied to pooled results
__global__ void k_final(const float* __restrict__ stats,
                        const float* __restrict__ gamma,
                        const float* __restrict__ beta,
                        const int* __restrict__ gcnt,
                        const float* __restrict__ gsum,
                        const float* __restrict__ gmax,
                        const float* __restrict__ gmin,
                        float* __restrict__ out) {
    int t = blockIdx.x * 256 + threadIdx.x;
    if (t >= GG * CC) return;
    int g = t >> 6, j = t & 63;
    float mean = stats[j] * (1.0f / NN);
    float var = stats[CC + j] * (1.0f / NN) - mean * mean;
    float sc = gamma[j] * rsqrtf(var + 1e-5f);
    float sh = beta[j] - mean * sc;
    int n = gcnt[g];
    if (n > 0) {
        out[g * 2 * CC + j] = sc * (gsum[t] / (float)n) + sh;
        out[g * 2 * CC + CC + j] = (sc >= 0.0f) ? sc * gmax[t] + sh
                                                : sc * gmin[t] + sh;
    } else {
        out[g * 2 * CC + j] = 0.0f;
        out[g * 2 * CC + CC + j] = -__builtin_inff();
    }
}

extern "C" void kernel_launch(void* const* d_in, const int* in_sizes, int n_in,
                              void* d_out, int out_size, void* d_ws, size_t ws_size,
                              hipStream_t stream) {
    const float* x = (const float*)d_in[0];
    const int* ei = (const int*)d_in[1];
    const float* ew = (const float*)d_in[2];
    const int* batch = (const int*)d_in[3];
    const float* W = (const float*)d_in[4];
    const float* b = (const float*)d_in[5];
    const float* a = (const float*)d_in[6];
    const float* gamma = (const float*)d_in[7];
    const float* beta = (const float*)d_in[8];
    float* out = (float*)d_out;

    float* ws = (float*)d_ws;
    float* dinv = ws;
    int* rps = (int*)(ws + 50048);
    int* rcnt = (int*)(ws + 2 * 50048);
    int* bin_cnt = (int*)(ws + 3 * 50048);
    float* stats = ws + 3 * 50048 + 256;
    int* gcnt = (int*)(stats + 256);
    float* gsum = (float*)(gcnt + 256);
    float* gmax = gsum + GG * CC;
    float* gmin = gmax + GG * CC;
    float* psum = gmin + GG * CC;              // KP*GG*CC
    float* psq = psum + KP * GG * CC;
    float* pmax = psq + KP * GG * CC;
    float* pmin = pmax + KP * GG * CC;
    int2* binbuf = (int2*)(pmin + KP * GG * CC);
    unsigned* csrc = (unsigned*)(binbuf + (size_t)BINS * CAPB);
    bf16* y = (bf16*)(csrc + (size_t)BINS * CAPB);
    bf16* h1 = y + (size_t)NN * CC;
    bf16* h2 = h1 + (size_t)NN * CC;

    dim3 blk(256);
    int gH = (NN + 3) / 4;

    k_prep<<<1, blk, 0, stream>>>(bin_cnt, stats);
    k_binA<<<GA, blk, 0, stream>>>(ei, ew, bin_cnt, binbuf);
    k_csr<<<BINS, blk, 0, stream>>>(bin_cnt, binbuf, dinv, rps, rcnt);
    k_linfold<<<gH, blk, 0, stream>>>(x, W, dinv, rps, rcnt, binbuf, csrc, y);

    k_hop8<<<gH, blk, 0, stream>>>(y, dinv, rps, rcnt, csrc, h1);
    k_hop8<<<gH, blk, 0, stream>>>(h1, dinv, rps, rcnt, csrc, h2);

    k_poolstat2<<<GG * KP, blk, 0, stream>>>(h2, b, a, batch, psum, psq, pmax,
                                             pmin, gcnt);
    k_red<<<GG / 4, blk, 0, stream>>>(psum, psq, pmax, pmin, gsum, gmax, gmin, stats);
    k_final<<<(GG * CC + 255) / 256, blk, 0, stream>>>(stats, gamma, beta, gcnt,
                                                       gsum, gmax, gmin, out);
}